// Round 3
// baseline (860.688 us; speedup 1.0000x reference)
//
#include <hip/hip_runtime.h>
#include <hip/hip_cooperative_groups.h>
#include <math.h>

namespace cg = cooperative_groups;

#define N_NODES 100000
#define N_EDGES 1600000
#define IN_DIM 128
#define HID_DIM 64
#define OUT_DIM 40

#define NPAD 102400

#define BUCKET_SHIFT 7
#define BUCKET_NODES 128
#define N_BUCKETS 782          // ceil(100000/128)
#define CHUNK 2048
#define N_CHUNKS 784           // 8 XCD groups x 98; 784*2048 >= N_EDGES

typedef _Float16 f16;
typedef _Float16 f16x2 __attribute__((ext_vector_type(2)));
typedef _Float16 f16x4 __attribute__((ext_vector_type(4)));
typedef _Float16 f16x8 __attribute__((ext_vector_type(8)));
typedef float f32x4 __attribute__((ext_vector_type(4)));

// -------- workspace layout --------
// ints:  hist[N_BUCKETS*N_CHUNKS] (TRANSPOSED: hist[b][c]) | base[N_BUCKETS*N_CHUNKS] |
//        bucketTotal[1024] | bucketBase[1024] | row_start[NPAD] | cnt[NPAD] | csr[E] | stage[E]
// floats: dinv[NPAD]
// f16:    h1p[N*64] | h2p[N*64 padded rows] | w1f[8192] | w2f[3072]
// NO memset needed: every buffer fully written before read each launch.

// ---------------- fused preprocessing (cooperative, 5 phases) ----------------
// Phase A: per-chunk LDS histogram over dst buckets (+ blocks 0/1 build MFMA
//          fragment-ordered W1/W2)
// Phase B: per-bucket exclusive scan over chunks -> base, bucketTotal
// Phase C: block 0 scans bucket totals -> bucketBase
// Phase D: deterministic scatter into bucket-grouped stage
// Phase E: per-bucket node hist + scan -> row_start/cnt/dinv + csr placement
__global__ __launch_bounds__(256, 4) void prep_kernel(
    const int* __restrict__ src, const int* __restrict__ dst,
    int* __restrict__ hist, int* __restrict__ base,
    int* __restrict__ bucketTotal, int* __restrict__ bucketBase,
    int* __restrict__ stage, int* __restrict__ csr,
    int* __restrict__ row_start, int* __restrict__ cnt, float* __restrict__ dinv,
    const float* __restrict__ W1, const float* __restrict__ W2,
    f16* __restrict__ w1f, f16* __restrict__ w2f)
{
    cg::grid_group gg = cg::this_grid();
    __shared__ int shmem[1564];
    int bid = blockIdx.x;
    int t = threadIdx.x;

    // ---- Phase A: chunk histograms (transposed store) + weight frags ----
    {
        int* lh = shmem;
        for (int b = t; b < N_BUCKETS; b += 256) lh[b] = 0;
        __syncthreads();
        int e0 = bid * CHUNK;
        for (int i = t; i < CHUNK; i += 256) {
            int e = e0 + i;
            if (e < N_EDGES) atomicAdd(&lh[dst[e] >> BUCKET_SHIFT], 1);
        }
        __syncthreads();
        for (int b = t; b < N_BUCKETS; b += 256) hist[b * N_CHUNKS + bid] = lh[b];
        if (bid == 0) {
            // wfrag W1: frag f=s*4+cc, lane L holds B[32s+(L>>4)*8+j][16cc+(L&15)]
            for (int g = t; g < 1024; g += 256) {
                int f = g >> 6, L = g & 63;
                int s = f >> 2, cc = f & 3;
                int q = L >> 4, n = L & 15;
                f16x8 v;
#pragma unroll
                for (int j = 0; j < 8; ++j)
                    v[j] = (f16)W1[(32 * s + 8 * q + j) * HID_DIM + 16 * cc + n];
                *(f16x8*)&w1f[(size_t)g * 8] = v;
            }
        } else if (bid == 1) {
            // wfrag W2 (cols 40..47 zero-padded)
            for (int g = t; g < 384; g += 256) {
                int f = g >> 6, L = g & 63;
                int s = f / 3, cc = f % 3;
                int q = L >> 4, n = L & 15;
                int col = 16 * cc + n;
                f16x8 v;
#pragma unroll
                for (int j = 0; j < 8; ++j)
                    v[j] = (col < OUT_DIM) ? (f16)W2[(32 * s + 8 * q + j) * OUT_DIM + col] : (f16)0.f;
                *(f16x8*)&w2f[(size_t)g * 8] = v;
            }
        }
    }
    __threadfence();
    gg.sync();

    // ---- Phase B: per-bucket exclusive scan over 784 chunks ----
    if (bid < N_BUCKETS) {
        int* lds = shmem;
        int v[4];
        int s = 0;
        for (int k = 0; k < 4; ++k) {
            int c = 4 * t + k;
            int cv = (c < N_CHUNKS) ? hist[bid * N_CHUNKS + c] : 0;
            v[k] = s;
            s += cv;
        }
        lds[t] = s;
        __syncthreads();
        for (int off = 1; off < 256; off <<= 1) {
            int val = (t >= off) ? lds[t - off] : 0;
            __syncthreads();
            lds[t] += val;
            __syncthreads();
        }
        int excl = (t == 0) ? 0 : lds[t - 1];
        for (int k = 0; k < 4; ++k) {
            int c = 4 * t + k;
            if (c < N_CHUNKS) base[bid * N_CHUNKS + c] = excl + v[k];
        }
        if (t == 255) bucketTotal[bid] = lds[255];
    }
    __threadfence();
    gg.sync();

    // ---- Phase C: scan 782 bucket totals (block 0) ----
    if (bid == 0) {
        int* lds = shmem;
        int v[4];
        int s = 0;
        for (int k = 0; k < 4; ++k) {
            int b = 4 * t + k;
            int cv = (b < N_BUCKETS) ? bucketTotal[b] : 0;
            v[k] = s;
            s += cv;
        }
        lds[t] = s;
        __syncthreads();
        for (int off = 1; off < 256; off <<= 1) {
            int val = (t >= off) ? lds[t - off] : 0;
            __syncthreads();
            lds[t] += val;
            __syncthreads();
        }
        int excl = (t == 0) ? 0 : lds[t - 1];
        for (int k = 0; k < 4; ++k) {
            int b = 4 * t + k;
            if (b < N_BUCKETS) bucketBase[b] = excl + v[k];
        }
    }
    __threadfence();
    gg.sync();

    // ---- Phase D: deterministic scatter into bucket-grouped stage ----
    {
        int* lbase = shmem;
        int* lcnt = shmem + N_BUCKETS;
        int chunk = (bid & 7) * 98 + (bid >> 3);   // bijection on [0,784)
        for (int b = t; b < N_BUCKETS; b += 256) {
            lbase[b] = base[b * N_CHUNKS + chunk] + bucketBase[b];
            lcnt[b] = 0;
        }
        __syncthreads();
        int e0 = chunk * CHUNK;
        for (int i = t; i < CHUNK; i += 256) {
            int e = e0 + i;
            if (e < N_EDGES) {
                int d = dst[e];
                int b = d >> BUCKET_SHIFT;
                int pos = lbase[b] + atomicAdd(&lcnt[b], 1);
                stage[pos] = ((d & (BUCKET_NODES - 1)) << 17) | src[e];
            }
        }
    }
    __threadfence();
    gg.sync();

    // ---- Phase E: per-bucket node hist + scan -> row_start/cnt/dinv + csr ----
    if (bid < N_BUCKETS) {
        int* lhist = shmem;
        int* lscan = shmem + BUCKET_NODES;
        int* lstart = shmem + 2 * BUCKET_NODES;
        int* lcur = shmem + 3 * BUCKET_NODES;
        int est = bucketBase[bid];
        int een = (bid == N_BUCKETS - 1) ? N_EDGES : bucketBase[bid + 1];
        if (t < BUCKET_NODES) { lhist[t] = 0; lcur[t] = 0; }
        __syncthreads();
        for (int e = est + t; e < een; e += 256) atomicAdd(&lhist[stage[e] >> 17], 1);
        __syncthreads();
        if (t < BUCKET_NODES) lscan[t] = lhist[t];
        __syncthreads();
        for (int off = 1; off < BUCKET_NODES; off <<= 1) {
            int val = (t >= off && t < BUCKET_NODES) ? lscan[t - off] : 0;
            __syncthreads();
            if (t < BUCKET_NODES) lscan[t] += val;
            __syncthreads();
        }
        if (t < BUCKET_NODES) {
            int myexcl = (t == 0) ? 0 : lscan[t - 1];
            lstart[t] = est + myexcl;
            int node = (bid << BUCKET_SHIFT) + t;
            if (node < N_NODES) {
                row_start[node] = est + myexcl;
                cnt[node] = lhist[t];
                dinv[node] = rsqrtf((float)lhist[t] + 1.0f);
            }
        }
        __syncthreads();
        for (int e = est + t; e < een; e += 256) {
            int rec = stage[e];
            int dl = rec >> 17;
            int pos = lstart[dl] + atomicAdd(&lcur[dl], 1);
            csr[pos] = rec & 0x1FFFF;
        }
    }
}

// ---------------- gemm1 (MFMA): h1p = f16( dinv * (x @ W1) ) ----------------
__global__ __launch_bounds__(256) void gemm1_kernel(const float* __restrict__ x,
                                                    const f16* __restrict__ w1f,
                                                    const float* __restrict__ dinv,
                                                    f16* __restrict__ h1p) {
    __shared__ f16 aT[1088 * 8];   // 17408 B
    int t = threadIdx.x;
    int nodeBase = blockIdx.x * 64;
    int L = t & 63;

    const f16x8* w1f8 = (const f16x8*)w1f;
    f16x8 bfrag[16];
#pragma unroll
    for (int f = 0; f < 16; ++f) bfrag[f] = w1f8[f * 64 + L];

#pragma unroll
    for (int i = 0; i < 8; ++i) {
        int idx = i * 256 + t;
        int node = idx >> 5;
        int col4 = idx & 31;
        int gnode = nodeBase + node;
        if (gnode >= N_NODES) gnode = N_NODES - 1;
        float4 v = *(const float4*)&x[(size_t)gnode * IN_DIM + col4 * 4];
        int w = node >> 4, m = node & 15;
        int s = col4 >> 3, q = (col4 >> 1) & 3, j0 = (col4 & 1) * 4;
        f16x4 h;
        h.x = (f16)v.x; h.y = (f16)v.y; h.z = (f16)v.z; h.w = (f16)v.w;
        int idx16 = (w * 4 + s) * 68 + 17 * q + m;
        *(f16x4*)&aT[idx16 * 8 + j0] = h;
    }
    __syncthreads();

    int wv = t >> 6;
    int q = L >> 4, m = L & 15;
    f32x4 acc[4] = {};
#pragma unroll
    for (int s = 0; s < 4; ++s) {
        f16x8 afrag = *(const f16x8*)&aT[((wv * 4 + s) * 68 + 17 * q + m) * 8];
#pragma unroll
        for (int c = 0; c < 4; ++c)
            acc[c] = __builtin_amdgcn_mfma_f32_16x16x32_f16(afrag, bfrag[s * 4 + c], acc[c], 0, 0, 0);
    }

#pragma unroll
    for (int r = 0; r < 4; ++r) {
        int node = nodeBase + 16 * wv + q * 4 + r;
        if (node < N_NODES) {
            float di = dinv[node];
#pragma unroll
            for (int c = 0; c < 4; ++c)
                h1p[(size_t)node * HID_DIM + 16 * c + m] = (f16)(acc[c][r] * di);
        }
    }
}

// ---------------- fused agg1 + gemm2 ----------------
// Phase 1: 8 nodes per wave (8-lane groups, lane reads f16x8=16B; one group =
// one 128B line), unroll-8 gathers in flight, masked tail.
// Phase 2: MFMA z @ W2 (cols zero-padded to 48) -> h2p (padded 128B rows).
#define ZSTR 72
#define H2STR 64
__global__ __launch_bounds__(256) void agg1mm_kernel(const f16* __restrict__ h1p,
                                                     const int* __restrict__ csr,
                                                     const int* __restrict__ row_start,
                                                     const int* __restrict__ cnt,
                                                     const float* __restrict__ dinv,
                                                     const float* __restrict__ b1,
                                                     const f16* __restrict__ w2f,
                                                     f16* __restrict__ h2p) {
    __shared__ f16 zT[64 * ZSTR];   // 9216 B
    int t = threadIdx.x;
    int nodeBase = blockIdx.x * 64;
    int wv = t >> 6;
    int L = t & 63;
    int g = L >> 3;       // node group 0..7 within wave
    int s = L & 7;        // sublane: f16x8 slot (dims 8s..8s+7)
    const f16x8* h8 = (const f16x8*)h1p;   // row stride 8 (f16x8 units)
    float bb[8];
#pragma unroll
    for (int j = 0; j < 8; ++j) bb[j] = b1[8 * s + j];

    for (int p = 0; p < 2; ++p) {
        int nodeLocal = 16 * wv + 8 * p + g;
        int node = nodeBase + nodeLocal;
        float acc[8];
#pragma unroll
        for (int j = 0; j < 8; ++j) acc[j] = 0.f;
        int lim = 0;
        const int* cp = csr;
        bool valid = (node < N_NODES);
        if (valid) {
            f16x8 sv = h8[(size_t)node * 8 + s];   // self loop
#pragma unroll
            for (int j = 0; j < 8; ++j) acc[j] = (float)sv[j];
            lim = cnt[node];
            cp = csr + row_start[node];
        }
        for (int k = 0; k < lim; k += 8) {
            int ii[8]; float mm[8];
#pragma unroll
            for (int u = 0; u < 8; ++u) {
                int kk = k + u;
                bool ok = (kk < lim);
                ii[u] = cp[ok ? kk : k];
                mm[u] = ok ? 1.f : 0.f;
            }
            f16x8 f[8];
#pragma unroll
            for (int u = 0; u < 8; ++u) f[u] = h8[(size_t)ii[u] * 8 + s];
#pragma unroll
            for (int j = 0; j < 8; ++j) {
                float t0 = 0.f;
#pragma unroll
                for (int u = 0; u < 8; ++u) t0 += mm[u] * (float)f[u][j];
                acc[j] += t0;
            }
        }
        f16x8 o;
        if (valid) {
            float di = dinv[node];
#pragma unroll
            for (int j = 0; j < 8; ++j) {
                float v = acc[j] * di + bb[j];
                o[j] = (f16)(v > 0.f ? v : 0.f);
            }
        } else {
#pragma unroll
            for (int j = 0; j < 8; ++j) o[j] = (f16)0.f;
        }
        *(f16x8*)&zT[nodeLocal * ZSTR + 8 * s] = o;
    }
    __syncthreads();

    // Phase 2: wave wv -> m-tile wv (nodes nodeBase+16*wv .. +15)
    int q = L >> 4, m = L & 15;
    const f16x8* w2f8 = (const f16x8*)w2f;
    f32x4 acc2[3] = {};
#pragma unroll
    for (int ks = 0; ks < 2; ++ks) {
        f16x8 afrag = *(const f16x8*)&zT[(16 * wv + m) * ZSTR + 32 * ks + 8 * q];
#pragma unroll
        for (int c = 0; c < 3; ++c)
            acc2[c] = __builtin_amdgcn_mfma_f32_16x16x32_f16(afrag, w2f8[(ks * 3 + c) * 64 + L], acc2[c], 0, 0, 0);
    }
#pragma unroll
    for (int r = 0; r < 4; ++r) {
        int node = nodeBase + 16 * wv + q * 4 + r;
        if (node < N_NODES) {
            float di = dinv[node];
            h2p[(size_t)node * H2STR + m]      = (f16)(acc2[0][r] * di);
            h2p[(size_t)node * H2STR + 16 + m] = (f16)(acc2[1][r] * di);
            if (m < 8)
                h2p[(size_t)node * H2STR + 32 + m] = (f16)(acc2[2][r] * di);
        }
    }
}

// agg2: 1 node per 5-lane group (each lane carries 16B of the 80B payload),
// h2p rows padded to 128B -> every gather is one aligned line.
// 12 nodes per wave, 48 nodes per block; unroll-8 with masked tail.
__global__ __launch_bounds__(256) void agg2_kernel(const f16* __restrict__ h2p,
                                                   const int* __restrict__ csr,
                                                   const int* __restrict__ row_start,
                                                   const int* __restrict__ cnt,
                                                   const float* __restrict__ dinv,
                                                   const float* __restrict__ b2,
                                                   float* __restrict__ out) {
    int t = threadIdx.x;
    int L = t & 63;
    int wv = t >> 6;
    int g = (L * 13) >> 6;            // == L/5 for L in [0,64)
    int s = L - 5 * g;                // == L%5 : f16x8 slot (dims 8s..8s+7)
    int node = blockIdx.x * 48 + wv * 12 + g;
    if (g >= 12 || node >= N_NODES) return;
    const f16x8* h8 = (const f16x8*)h2p;  // row stride 8 (f16x8 units, padded)
    float acc[8];
    {
        f16x8 sv = h8[(size_t)node * 8 + s];   // self loop
#pragma unroll
        for (int j = 0; j < 8; ++j) acc[j] = (float)sv[j];
    }
    int lim = cnt[node];
    const int* cp = csr + row_start[node];
    for (int k = 0; k < lim; k += 8) {
        int ii[8]; float mm[8];
#pragma unroll
        for (int u = 0; u < 8; ++u) {
            int kk = k + u;
            bool ok = (kk < lim);
            ii[u] = cp[ok ? kk : k];
            mm[u] = ok ? 1.f : 0.f;
        }
        f16x8 f[8];
#pragma unroll
        for (int u = 0; u < 8; ++u) f[u] = h8[(size_t)ii[u] * 8 + s];
#pragma unroll
        for (int j = 0; j < 8; ++j) {
            float t0 = 0.f;
#pragma unroll
            for (int u = 0; u < 8; ++u) t0 += mm[u] * (float)f[u][j];
            acc[j] += t0;
        }
    }
    float di = dinv[node];
    float4 o0, o1;
    o0.x = acc[0] * di + b2[8 * s + 0];
    o0.y = acc[1] * di + b2[8 * s + 1];
    o0.z = acc[2] * di + b2[8 * s + 2];
    o0.w = acc[3] * di + b2[8 * s + 3];
    o1.x = acc[4] * di + b2[8 * s + 4];
    o1.y = acc[5] * di + b2[8 * s + 5];
    o1.z = acc[6] * di + b2[8 * s + 6];
    o1.w = acc[7] * di + b2[8 * s + 7];
    *(float4*)&out[(size_t)node * OUT_DIM + 8 * s] = o0;
    *(float4*)&out[(size_t)node * OUT_DIM + 8 * s + 4] = o1;
}

extern "C" void kernel_launch(void* const* d_in, const int* in_sizes, int n_in,
                              void* d_out, int out_size, void* d_ws, size_t ws_size,
                              hipStream_t stream) {
    const float* x  = (const float*)d_in[0];
    const int*   ei = (const int*)d_in[1];      // [2, E] int32
    const float* W1 = (const float*)d_in[2];
    const float* b1 = (const float*)d_in[3];
    const float* W2 = (const float*)d_in[4];
    const float* b2 = (const float*)d_in[5];
    float* out = (float*)d_out;

    const int* src = ei;
    const int* dst = ei + N_EDGES;

    int* wsi        = (int*)d_ws;
    int* hist       = wsi;
    int* base       = hist + N_BUCKETS * N_CHUNKS;
    int* bucketTotal= base + N_BUCKETS * N_CHUNKS;
    int* bucketBase = bucketTotal + 1024;
    int* row_start  = bucketBase + 1024;
    int* cnt        = row_start + NPAD;
    int* csr        = cnt + NPAD;
    int* stage      = csr + N_EDGES;
    float* dinv     = (float*)(stage + N_EDGES);
    f16*   h1p      = (f16*)(dinv + NPAD);
    f16*   h2p      = h1p + (size_t)N_NODES * HID_DIM;
    f16*   w1f      = h2p + (size_t)N_NODES * H2STR;     // h2p padded: N*64 f16
    f16*   w2f      = w1f + 8192;                        // 3072 f16

    // D1: fused preprocessing (cooperative, 5 phases with grid.sync)
    {
        void* args[] = {
            (void*)&src, (void*)&dst,
            (void*)&hist, (void*)&base,
            (void*)&bucketTotal, (void*)&bucketBase,
            (void*)&stage, (void*)&csr,
            (void*)&row_start, (void*)&cnt, (void*)&dinv,
            (void*)&W1, (void*)&W2,
            (void*)&w1f, (void*)&w2f
        };
        hipLaunchCooperativeKernel((const void*)prep_kernel, dim3(N_CHUNKS), dim3(256),
                                   args, 0, stream);
    }
    // D2-D4: gemm1 -> fused agg1+gemm2 -> agg2
    gemm1_kernel<<<(N_NODES + 63) / 64, 256, 0, stream>>>(x, w1f, dinv, h1p);
    agg1mm_kernel<<<(N_NODES + 63) / 64, 256, 0, stream>>>(h1p, csr, row_start, cnt, dinv, b1, w2f, h2p);
    agg2_kernel<<<(N_NODES + 47) / 48, 256, 0, stream>>>(h2p, csr, row_start, cnt, dinv, b2, out);
}

// Round 4
// 638.207 us; speedup vs baseline: 1.3486x; 1.3486x over previous
//
#include <hip/hip_runtime.h>
#include <math.h>

#define N_NODES 100000
#define N_EDGES 1600000
#define IN_DIM 128
#define HID_DIM 64
#define OUT_DIM 40

#define NPAD 102400
#define EBLK 1563              // ceil((N_EDGES/4)/256) edge-quad blocks

typedef _Float16 f16;
typedef _Float16 f16x4 __attribute__((ext_vector_type(4)));
typedef _Float16 f16x8 __attribute__((ext_vector_type(8)));
typedef float f32x4 __attribute__((ext_vector_type(4)));

// -------- workspace layout --------
// ints:  row_start[NPAD] | cnt[NPAD] | cur[NPAD] | csr[E]
// floats: dinv[NPAD]
// f16:    h1p[N*64] | h2p[N*64 padded rows] | w1f[8192] | w2f[3072]
// cnt is zeroed via hipMemsetAsync each launch; everything else fully written
// before read.

// 1) degree count via device atomics (cnt pre-zeroed). Blocks EBLK/EBLK+1
//    build the MFMA fragment-ordered W1/W2.
__global__ __launch_bounds__(256) void count_kernel(const int* __restrict__ dst,
                                                    int* __restrict__ cnt,
                                                    const float* __restrict__ W1,
                                                    const float* __restrict__ W2,
                                                    f16* __restrict__ w1f,
                                                    f16* __restrict__ w2f) {
    int bid = blockIdx.x;
    int t = threadIdx.x;
    if (bid < EBLK) {
        int i = bid * 256 + t;
        if (i < N_EDGES / 4) {
            int4 d = ((const int4*)dst)[i];
            atomicAdd(&cnt[d.x], 1);
            atomicAdd(&cnt[d.y], 1);
            atomicAdd(&cnt[d.z], 1);
            atomicAdd(&cnt[d.w], 1);
        }
    } else if (bid == EBLK) {
        // wfrag W1: frag f=s*4+cc, lane L holds B[32s+(L>>4)*8+j][16cc+(L&15)]
        for (int g = t; g < 1024; g += 256) {
            int f = g >> 6, L = g & 63;
            int s = f >> 2, cc = f & 3;
            int q = L >> 4, n = L & 15;
            f16x8 v;
#pragma unroll
            for (int j = 0; j < 8; ++j)
                v[j] = (f16)W1[(32 * s + 8 * q + j) * HID_DIM + 16 * cc + n];
            *(f16x8*)&w1f[(size_t)g * 8] = v;
        }
    } else {
        // wfrag W2 (cols 40..47 zero-padded)
        for (int g = t; g < 384; g += 256) {
            int f = g >> 6, L = g & 63;
            int s = f / 3, cc = f % 3;
            int q = L >> 4, n = L & 15;
            int col = 16 * cc + n;
            f16x8 v;
#pragma unroll
            for (int j = 0; j < 8; ++j)
                v[j] = (col < OUT_DIM) ? (f16)W2[(32 * s + 8 * q + j) * OUT_DIM + col] : (f16)0.f;
            *(f16x8*)&w2f[(size_t)g * 8] = v;
        }
    }
}

// 2) single-block exclusive scan over cnt -> row_start, cur(copy), dinv.
//    1024 threads, 98 contiguous nodes each; LDS scan of per-thread sums.
#define SCAN_T 1024
#define SCAN_PER 98
__global__ __launch_bounds__(SCAN_T) void scan_kernel(const int* __restrict__ cnt,
                                                      int* __restrict__ row_start,
                                                      int* __restrict__ cur,
                                                      float* __restrict__ dinv) {
    __shared__ int lds[SCAN_T];
    int t = threadIdx.x;
    int n0 = t * SCAN_PER;
    int n1 = n0 + SCAN_PER; if (n1 > N_NODES) n1 = N_NODES;
    int s = 0;
    for (int n = n0; n < n1; ++n) s += cnt[n];
    lds[t] = s;
    __syncthreads();
    for (int off = 1; off < SCAN_T; off <<= 1) {
        int val = (t >= off) ? lds[t - off] : 0;
        __syncthreads();
        lds[t] += val;
        __syncthreads();
    }
    int running = (t == 0) ? 0 : lds[t - 1];
    for (int n = n0; n < n1; ++n) {
        int c = cnt[n];
        row_start[n] = running;
        cur[n] = running;
        dinv[n] = rsqrtf((float)c + 1.0f);
        running += c;
    }
}

// 3) scatter edges into CSR via per-row atomic cursors (order within a row is
//    arbitrary — sums are order-insensitive at f32 well below f16 tolerance).
__global__ __launch_bounds__(256) void scatter_kernel(const int* __restrict__ src,
                                                      const int* __restrict__ dst,
                                                      int* __restrict__ cur,
                                                      int* __restrict__ csr) {
    int i = blockIdx.x * 256 + threadIdx.x;
    if (i >= N_EDGES / 4) return;
    int4 sv = ((const int4*)src)[i];
    int4 dv = ((const int4*)dst)[i];
    csr[atomicAdd(&cur[dv.x], 1)] = sv.x;
    csr[atomicAdd(&cur[dv.y], 1)] = sv.y;
    csr[atomicAdd(&cur[dv.z], 1)] = sv.z;
    csr[atomicAdd(&cur[dv.w], 1)] = sv.w;
}

// ---------------- gemm1 (MFMA): h1p = f16( dinv * (x @ W1) ) ----------------
__global__ __launch_bounds__(256) void gemm1_kernel(const float* __restrict__ x,
                                                    const f16* __restrict__ w1f,
                                                    const float* __restrict__ dinv,
                                                    f16* __restrict__ h1p) {
    __shared__ f16 aT[1088 * 8];   // 17408 B
    int t = threadIdx.x;
    int nodeBase = blockIdx.x * 64;
    int L = t & 63;

    const f16x8* w1f8 = (const f16x8*)w1f;
    f16x8 bfrag[16];
#pragma unroll
    for (int f = 0; f < 16; ++f) bfrag[f] = w1f8[f * 64 + L];

#pragma unroll
    for (int i = 0; i < 8; ++i) {
        int idx = i * 256 + t;
        int node = idx >> 5;
        int col4 = idx & 31;
        int gnode = nodeBase + node;
        if (gnode >= N_NODES) gnode = N_NODES - 1;
        float4 v = *(const float4*)&x[(size_t)gnode * IN_DIM + col4 * 4];
        int w = node >> 4, m = node & 15;
        int s = col4 >> 3, q = (col4 >> 1) & 3, j0 = (col4 & 1) * 4;
        f16x4 h;
        h.x = (f16)v.x; h.y = (f16)v.y; h.z = (f16)v.z; h.w = (f16)v.w;
        int idx16 = (w * 4 + s) * 68 + 17 * q + m;
        *(f16x4*)&aT[idx16 * 8 + j0] = h;
    }
    __syncthreads();

    int wv = t >> 6;
    int q = L >> 4, m = L & 15;
    f32x4 acc[4] = {};
#pragma unroll
    for (int s = 0; s < 4; ++s) {
        f16x8 afrag = *(const f16x8*)&aT[((wv * 4 + s) * 68 + 17 * q + m) * 8];
#pragma unroll
        for (int c = 0; c < 4; ++c)
            acc[c] = __builtin_amdgcn_mfma_f32_16x16x32_f16(afrag, bfrag[s * 4 + c], acc[c], 0, 0, 0);
    }

#pragma unroll
    for (int r = 0; r < 4; ++r) {
        int node = nodeBase + 16 * wv + q * 4 + r;
        if (node < N_NODES) {
            float di = dinv[node];
#pragma unroll
            for (int c = 0; c < 4; ++c)
                h1p[(size_t)node * HID_DIM + 16 * c + m] = (f16)(acc[c][r] * di);
        }
    }
}

// ---------------- fused agg1 + gemm2 ----------------
// Phase 1: 8 nodes per wave (8-lane groups, lane reads f16x8=16B; one group =
// one 128B line), unroll-8 gathers in flight, masked tail.
// Phase 2: MFMA z @ W2 (cols zero-padded to 48) -> h2p (padded 128B rows).
#define ZSTR 72
#define H2STR 64
__global__ __launch_bounds__(256) void agg1mm_kernel(const f16* __restrict__ h1p,
                                                     const int* __restrict__ csr,
                                                     const int* __restrict__ row_start,
                                                     const int* __restrict__ cnt,
                                                     const float* __restrict__ dinv,
                                                     const float* __restrict__ b1,
                                                     const f16* __restrict__ w2f,
                                                     f16* __restrict__ h2p) {
    __shared__ f16 zT[64 * ZSTR];   // 9216 B
    int t = threadIdx.x;
    int nodeBase = blockIdx.x * 64;
    int wv = t >> 6;
    int L = t & 63;
    int g = L >> 3;       // node group 0..7 within wave
    int s = L & 7;        // sublane: f16x8 slot (dims 8s..8s+7)
    const f16x8* h8 = (const f16x8*)h1p;   // row stride 8 (f16x8 units)
    float bb[8];
#pragma unroll
    for (int j = 0; j < 8; ++j) bb[j] = b1[8 * s + j];

    for (int p = 0; p < 2; ++p) {
        int nodeLocal = 16 * wv + 8 * p + g;
        int node = nodeBase + nodeLocal;
        float acc[8];
#pragma unroll
        for (int j = 0; j < 8; ++j) acc[j] = 0.f;
        int lim = 0;
        const int* cp = csr;
        bool valid = (node < N_NODES);
        if (valid) {
            f16x8 sv = h8[(size_t)node * 8 + s];   // self loop
#pragma unroll
            for (int j = 0; j < 8; ++j) acc[j] = (float)sv[j];
            lim = cnt[node];
            cp = csr + row_start[node];
        }
        for (int k = 0; k < lim; k += 8) {
            int ii[8]; float mm[8];
#pragma unroll
            for (int u = 0; u < 8; ++u) {
                int kk = k + u;
                bool ok = (kk < lim);
                ii[u] = cp[ok ? kk : k];
                mm[u] = ok ? 1.f : 0.f;
            }
            f16x8 f[8];
#pragma unroll
            for (int u = 0; u < 8; ++u) f[u] = h8[(size_t)ii[u] * 8 + s];
#pragma unroll
            for (int j = 0; j < 8; ++j) {
                float t0 = 0.f;
#pragma unroll
                for (int u = 0; u < 8; ++u) t0 += mm[u] * (float)f[u][j];
                acc[j] += t0;
            }
        }
        f16x8 o;
        if (valid) {
            float di = dinv[node];
#pragma unroll
            for (int j = 0; j < 8; ++j) {
                float v = acc[j] * di + bb[j];
                o[j] = (f16)(v > 0.f ? v : 0.f);
            }
        } else {
#pragma unroll
            for (int j = 0; j < 8; ++j) o[j] = (f16)0.f;
        }
        *(f16x8*)&zT[nodeLocal * ZSTR + 8 * s] = o;
    }
    __syncthreads();

    // Phase 2: wave wv -> m-tile wv (nodes nodeBase+16*wv .. +15)
    int q = L >> 4, m = L & 15;
    const f16x8* w2f8 = (const f16x8*)w2f;
    f32x4 acc2[3] = {};
#pragma unroll
    for (int ks = 0; ks < 2; ++ks) {
        f16x8 afrag = *(const f16x8*)&zT[(16 * wv + m) * ZSTR + 32 * ks + 8 * q];
#pragma unroll
        for (int c = 0; c < 3; ++c)
            acc2[c] = __builtin_amdgcn_mfma_f32_16x16x32_f16(afrag, w2f8[(ks * 3 + c) * 64 + L], acc2[c], 0, 0, 0);
    }
#pragma unroll
    for (int r = 0; r < 4; ++r) {
        int node = nodeBase + 16 * wv + q * 4 + r;
        if (node < N_NODES) {
            float di = dinv[node];
            h2p[(size_t)node * H2STR + m]      = (f16)(acc2[0][r] * di);
            h2p[(size_t)node * H2STR + 16 + m] = (f16)(acc2[1][r] * di);
            if (m < 8)
                h2p[(size_t)node * H2STR + 32 + m] = (f16)(acc2[2][r] * di);
        }
    }
}

// agg2: 1 node per 5-lane group (each lane carries 16B of the 80B payload),
// h2p rows padded to 128B -> every gather is one aligned line.
// 12 nodes per wave, 48 nodes per block; unroll-8 with masked tail.
__global__ __launch_bounds__(256) void agg2_kernel(const f16* __restrict__ h2p,
                                                   const int* __restrict__ csr,
                                                   const int* __restrict__ row_start,
                                                   const int* __restrict__ cnt,
                                                   const float* __restrict__ dinv,
                                                   const float* __restrict__ b2,
                                                   float* __restrict__ out) {
    int t = threadIdx.x;
    int L = t & 63;
    int wv = t >> 6;
    int g = (L * 13) >> 6;            // == L/5 for L in [0,64)
    int s = L - 5 * g;                // == L%5 : f16x8 slot (dims 8s..8s+7)
    int node = blockIdx.x * 48 + wv * 12 + g;
    if (g >= 12 || node >= N_NODES) return;
    const f16x8* h8 = (const f16x8*)h2p;  // row stride 8 (f16x8 units, padded)
    float acc[8];
    {
        f16x8 sv = h8[(size_t)node * 8 + s];   // self loop
#pragma unroll
        for (int j = 0; j < 8; ++j) acc[j] = (float)sv[j];
    }
    int lim = cnt[node];
    const int* cp = csr + row_start[node];
    for (int k = 0; k < lim; k += 8) {
        int ii[8]; float mm[8];
#pragma unroll
        for (int u = 0; u < 8; ++u) {
            int kk = k + u;
            bool ok = (kk < lim);
            ii[u] = cp[ok ? kk : k];
            mm[u] = ok ? 1.f : 0.f;
        }
        f16x8 f[8];
#pragma unroll
        for (int u = 0; u < 8; ++u) f[u] = h8[(size_t)ii[u] * 8 + s];
#pragma unroll
        for (int j = 0; j < 8; ++j) {
            float t0 = 0.f;
#pragma unroll
            for (int u = 0; u < 8; ++u) t0 += mm[u] * (float)f[u][j];
            acc[j] += t0;
        }
    }
    float di = dinv[node];
    float4 o0, o1;
    o0.x = acc[0] * di + b2[8 * s + 0];
    o0.y = acc[1] * di + b2[8 * s + 1];
    o0.z = acc[2] * di + b2[8 * s + 2];
    o0.w = acc[3] * di + b2[8 * s + 3];
    o1.x = acc[4] * di + b2[8 * s + 4];
    o1.y = acc[5] * di + b2[8 * s + 5];
    o1.z = acc[6] * di + b2[8 * s + 6];
    o1.w = acc[7] * di + b2[8 * s + 7];
    *(float4*)&out[(size_t)node * OUT_DIM + 8 * s] = o0;
    *(float4*)&out[(size_t)node * OUT_DIM + 8 * s + 4] = o1;
}

extern "C" void kernel_launch(void* const* d_in, const int* in_sizes, int n_in,
                              void* d_out, int out_size, void* d_ws, size_t ws_size,
                              hipStream_t stream) {
    const float* x  = (const float*)d_in[0];
    const int*   ei = (const int*)d_in[1];      // [2, E] int32
    const float* W1 = (const float*)d_in[2];
    const float* b1 = (const float*)d_in[3];
    const float* W2 = (const float*)d_in[4];
    const float* b2 = (const float*)d_in[5];
    float* out = (float*)d_out;

    const int* src = ei;
    const int* dst = ei + N_EDGES;

    int* wsi        = (int*)d_ws;
    int* row_start  = wsi;
    int* cnt        = row_start + NPAD;
    int* cur        = cnt + NPAD;
    int* csr        = cur + NPAD;
    float* dinv     = (float*)(csr + N_EDGES);
    f16*   h1p      = (f16*)(dinv + NPAD);
    f16*   h2p      = h1p + (size_t)N_NODES * HID_DIM;
    f16*   w1f      = h2p + (size_t)N_NODES * H2STR;     // h2p padded: N*64 f16
    f16*   w2f      = w1f + 8192;                        // 3072 f16

    // D0: zero the degree counters (only buffer needing init)
    hipMemsetAsync(cnt, 0, N_NODES * sizeof(int), stream);
    // D1: degree count + weight-fragment build
    count_kernel<<<EBLK + 2, 256, 0, stream>>>(dst, cnt, W1, W2, w1f, w2f);
    // D2: single-block scan -> row_start / cur / dinv
    scan_kernel<<<1, SCAN_T, 0, stream>>>(cnt, row_start, cur, dinv);
    // D3: scatter edges into CSR (arbitrary within-row order)
    scatter_kernel<<<EBLK, 256, 0, stream>>>(src, dst, cur, csr);
    // D4-D6: gemm1 -> fused agg1+gemm2 -> agg2
    gemm1_kernel<<<(N_NODES + 63) / 64, 256, 0, stream>>>(x, w1f, dinv, h1p);
    agg1mm_kernel<<<(N_NODES + 63) / 64, 256, 0, stream>>>(h1p, csr, row_start, cnt, dinv, b1, w2f, h2p);
    agg2_kernel<<<(N_NODES + 47) / 48, 256, 0, stream>>>(h2p, csr, row_start, cnt, dinv, b2, out);
}

// Round 5
// 198.639 us; speedup vs baseline: 4.3329x; 3.2129x over previous
//
#include <hip/hip_runtime.h>
#include <math.h>

#define N_NODES 100000
#define N_EDGES 1600000
#define IN_DIM 128
#define HID_DIM 64
#define OUT_DIM 40

#define NPAD 102400

#define BUCKET_SHIFT 7
#define BUCKET_NODES 128
#define N_BUCKETS 782          // ceil(100000/128)
#define CHUNK 8192
#define N_CHUNKS 200           // 8 XCD groups x 25; 200*8192 >= N_EDGES

typedef _Float16 f16;
typedef _Float16 f16x4 __attribute__((ext_vector_type(4)));
typedef _Float16 f16x8 __attribute__((ext_vector_type(8)));
typedef float f32x4 __attribute__((ext_vector_type(4)));

// -------- workspace layout --------
// ints:  hist[N_BUCKETS*N_CHUNKS] (TRANSPOSED: hist[b][c]) | base[N_BUCKETS*N_CHUNKS] |
//        bucketTotal[1024] | bucketBase[1024] | row_start[NPAD] | cnt[NPAD] | csr[E] | stage[E]
// floats: dinv[NPAD]
// f16:    h1p[N*64] | h2p[N*64 padded rows] | w1f[8192] | w2f[3072]
// NO memset needed: every buffer fully written before read each launch.
// All sorting atomics are LDS-local (global far-atomics measured >=150us for
// this edge count in round 3 — avoid).

// 1) per-chunk LDS histogram over dst buckets (jobs 0..199, 1024 thr, int4
//    loads); jobs 200/201 build the MFMA fragment-ordered W1/W2.
__global__ __launch_bounds__(1024) void hist_kernel(const int* __restrict__ dst,
                                                    int* __restrict__ hist,
                                                    const float* __restrict__ W1,
                                                    const float* __restrict__ W2,
                                                    f16* __restrict__ w1f,
                                                    f16* __restrict__ w2f) {
    __shared__ int lh[N_BUCKETS];
    int c = blockIdx.x;
    int t = threadIdx.x;
    if (c < N_CHUNKS) {
        for (int b = t; b < N_BUCKETS; b += 1024) lh[b] = 0;
        __syncthreads();
        const int4* d4 = (const int4*)dst;
        int i0 = c * (CHUNK / 4);
#pragma unroll
        for (int r = 0; r < 2; ++r) {
            int idx = i0 + r * 1024 + t;
            if (idx < N_EDGES / 4) {
                int4 d = d4[idx];
                atomicAdd(&lh[d.x >> BUCKET_SHIFT], 1);
                atomicAdd(&lh[d.y >> BUCKET_SHIFT], 1);
                atomicAdd(&lh[d.z >> BUCKET_SHIFT], 1);
                atomicAdd(&lh[d.w >> BUCKET_SHIFT], 1);
            }
        }
        __syncthreads();
        for (int b = t; b < N_BUCKETS; b += 1024) hist[b * N_CHUNKS + c] = lh[b];
    } else if (c == N_CHUNKS) {
        // wfrag W1: frag f=s*4+cc, lane L holds B[32s+(L>>4)*8+j][16cc+(L&15)]
        if (t < 1024) {
            int g = t;
            int f = g >> 6, L = g & 63;
            int s = f >> 2, cc = f & 3;
            int q = L >> 4, n = L & 15;
            f16x8 v;
#pragma unroll
            for (int j = 0; j < 8; ++j)
                v[j] = (f16)W1[(32 * s + 8 * q + j) * HID_DIM + 16 * cc + n];
            *(f16x8*)&w1f[(size_t)g * 8] = v;
        }
    } else {
        // wfrag W2 (cols 40..47 zero-padded)
        if (t < 384) {
            int g = t;
            int f = g >> 6, L = g & 63;
            int s = f / 3, cc = f % 3;
            int q = L >> 4, n = L & 15;
            int col = 16 * cc + n;
            f16x8 v;
#pragma unroll
            for (int j = 0; j < 8; ++j)
                v[j] = (col < OUT_DIM) ? (f16)W2[(32 * s + 8 * q + j) * OUT_DIM + col] : (f16)0.f;
            *(f16x8*)&w2f[(size_t)g * 8] = v;
        }
    }
}

// 2) per-bucket exclusive scan over 200 chunks -> base[b][c], bucketTotal[b].
__global__ __launch_bounds__(256) void scan_chunks_kernel(const int* __restrict__ hist,
                                                          int* __restrict__ base,
                                                          int* __restrict__ bucketTotal) {
    __shared__ int lds[256];
    int b = blockIdx.x;
    int t = threadIdx.x;
    int cv = (t < N_CHUNKS) ? hist[b * N_CHUNKS + t] : 0;
    lds[t] = cv;
    __syncthreads();
    for (int off = 1; off < 256; off <<= 1) {
        int val = (t >= off) ? lds[t - off] : 0;
        __syncthreads();
        lds[t] += val;
        __syncthreads();
    }
    if (t < N_CHUNKS) base[b * N_CHUNKS + t] = lds[t] - cv;   // exclusive
    if (t == 255) bucketTotal[b] = lds[255];
}

// 3) exclusive scan over 782 bucket totals -> bucketBase
__global__ __launch_bounds__(256) void scan_buckets_kernel(const int* __restrict__ bucketTotal,
                                                           int* __restrict__ bucketBase) {
    __shared__ int lds[256];
    int t = threadIdx.x;
    int v[4];
    int s = 0;
    for (int k = 0; k < 4; ++k) {
        int b = 4 * t + k;
        int cv = (b < N_BUCKETS) ? bucketTotal[b] : 0;
        v[k] = s;
        s += cv;
    }
    lds[t] = s;
    __syncthreads();
    for (int off = 1; off < 256; off <<= 1) {
        int val = (t >= off) ? lds[t - off] : 0;
        __syncthreads();
        lds[t] += val;
        __syncthreads();
    }
    int excl = (t == 0) ? 0 : lds[t - 1];
    for (int k = 0; k < 4; ++k) {
        int b = 4 * t + k;
        if (b < N_BUCKETS) bucketBase[b] = excl + v[k];
    }
}

// 4) deterministic scatter into bucket-grouped stage; LDS slice counters only.
//    1024 threads, int4 edge loads.
__global__ __launch_bounds__(1024) void scatter_kernel(const int* __restrict__ src,
                                                       const int* __restrict__ dst,
                                                       const int* __restrict__ base,
                                                       const int* __restrict__ bucketBase,
                                                       int* __restrict__ stage) {
    __shared__ int lbase[N_BUCKETS];
    __shared__ int lcnt[N_BUCKETS];
    int bid = blockIdx.x;
    int chunk = (bid & 7) * 25 + (bid >> 3);   // bijection on [0,200)
    int t = threadIdx.x;
    for (int b = t; b < N_BUCKETS; b += 1024) {
        lbase[b] = base[b * N_CHUNKS + chunk] + bucketBase[b];
        lcnt[b] = 0;
    }
    __syncthreads();
    const int4* s4 = (const int4*)src;
    const int4* d4 = (const int4*)dst;
    int i0 = chunk * (CHUNK / 4);
#pragma unroll
    for (int r = 0; r < 2; ++r) {
        int idx = i0 + r * 1024 + t;
        if (idx < N_EDGES / 4) {
            int4 sv = s4[idx];
            int4 dv = d4[idx];
            int d, b, pos;
            d = dv.x; b = d >> BUCKET_SHIFT;
            pos = lbase[b] + atomicAdd(&lcnt[b], 1);
            stage[pos] = ((d & (BUCKET_NODES - 1)) << 17) | sv.x;
            d = dv.y; b = d >> BUCKET_SHIFT;
            pos = lbase[b] + atomicAdd(&lcnt[b], 1);
            stage[pos] = ((d & (BUCKET_NODES - 1)) << 17) | sv.y;
            d = dv.z; b = d >> BUCKET_SHIFT;
            pos = lbase[b] + atomicAdd(&lcnt[b], 1);
            stage[pos] = ((d & (BUCKET_NODES - 1)) << 17) | sv.z;
            d = dv.w; b = d >> BUCKET_SHIFT;
            pos = lbase[b] + atomicAdd(&lcnt[b], 1);
            stage[pos] = ((d & (BUCKET_NODES - 1)) << 17) | sv.w;
        }
    }
}

// 5) one block per bucket: LDS node histogram + scan -> row_start/cnt/dinv + csr place
__global__ __launch_bounds__(256) void place_kernel(const int* __restrict__ stage,
                                                    const int* __restrict__ bucketBase,
                                                    int* __restrict__ csr,
                                                    int* __restrict__ row_start,
                                                    int* __restrict__ cnt,
                                                    float* __restrict__ dinv) {
    __shared__ int lhist[BUCKET_NODES];
    __shared__ int lscan[BUCKET_NODES];
    __shared__ int lstart[BUCKET_NODES];
    __shared__ int lcur[BUCKET_NODES];
    int b = blockIdx.x;
    int t = threadIdx.x;
    int est = bucketBase[b];
    int een = (b == N_BUCKETS - 1) ? N_EDGES : bucketBase[b + 1];
    if (t < BUCKET_NODES) { lhist[t] = 0; lcur[t] = 0; }
    __syncthreads();
    for (int e = est + t; e < een; e += 256) atomicAdd(&lhist[stage[e] >> 17], 1);
    __syncthreads();
    if (t < BUCKET_NODES) lscan[t] = lhist[t];
    __syncthreads();
    for (int off = 1; off < BUCKET_NODES; off <<= 1) {
        int val = (t >= off && t < BUCKET_NODES) ? lscan[t - off] : 0;
        __syncthreads();
        if (t < BUCKET_NODES) lscan[t] += val;
        __syncthreads();
    }
    if (t < BUCKET_NODES) {
        int myexcl = (t == 0) ? 0 : lscan[t - 1];
        lstart[t] = est + myexcl;
        int node = (b << BUCKET_SHIFT) + t;
        if (node < N_NODES) {
            row_start[node] = est + myexcl;
            cnt[node] = lhist[t];
            dinv[node] = rsqrtf((float)lhist[t] + 1.0f);
        }
    }
    __syncthreads();
    for (int e = est + t; e < een; e += 256) {
        int rec = stage[e];
        int dl = rec >> 17;
        int pos = lstart[dl] + atomicAdd(&lcur[dl], 1);
        csr[pos] = rec & 0x1FFFF;
    }
}

// ---------------- gemm1 (MFMA): h1p = f16( dinv * (x @ W1) ) ----------------
__global__ __launch_bounds__(256) void gemm1_kernel(const float* __restrict__ x,
                                                    const f16* __restrict__ w1f,
                                                    const float* __restrict__ dinv,
                                                    f16* __restrict__ h1p) {
    __shared__ f16 aT[1088 * 8];   // 17408 B
    int t = threadIdx.x;
    int nodeBase = blockIdx.x * 64;
    int L = t & 63;

    const f16x8* w1f8 = (const f16x8*)w1f;
    f16x8 bfrag[16];
#pragma unroll
    for (int f = 0; f < 16; ++f) bfrag[f] = w1f8[f * 64 + L];

#pragma unroll
    for (int i = 0; i < 8; ++i) {
        int idx = i * 256 + t;
        int node = idx >> 5;
        int col4 = idx & 31;
        int gnode = nodeBase + node;
        if (gnode >= N_NODES) gnode = N_NODES - 1;
        float4 v = *(const float4*)&x[(size_t)gnode * IN_DIM + col4 * 4];
        int w = node >> 4, m = node & 15;
        int s = col4 >> 3, q = (col4 >> 1) & 3, j0 = (col4 & 1) * 4;
        f16x4 h;
        h.x = (f16)v.x; h.y = (f16)v.y; h.z = (f16)v.z; h.w = (f16)v.w;
        int idx16 = (w * 4 + s) * 68 + 17 * q + m;
        *(f16x4*)&aT[idx16 * 8 + j0] = h;
    }
    __syncthreads();

    int wv = t >> 6;
    int q = L >> 4, m = L & 15;
    f32x4 acc[4] = {};
#pragma unroll
    for (int s = 0; s < 4; ++s) {
        f16x8 afrag = *(const f16x8*)&aT[((wv * 4 + s) * 68 + 17 * q + m) * 8];
#pragma unroll
        for (int c = 0; c < 4; ++c)
            acc[c] = __builtin_amdgcn_mfma_f32_16x16x32_f16(afrag, bfrag[s * 4 + c], acc[c], 0, 0, 0);
    }

#pragma unroll
    for (int r = 0; r < 4; ++r) {
        int node = nodeBase + 16 * wv + q * 4 + r;
        if (node < N_NODES) {
            float di = dinv[node];
#pragma unroll
            for (int c = 0; c < 4; ++c)
                h1p[(size_t)node * HID_DIM + 16 * c + m] = (f16)(acc[c][r] * di);
        }
    }
}

// ---------------- fused agg1 + gemm2 ----------------
// Phase 1: 8 nodes per wave (8-lane groups, lane reads f16x8=16B; one group =
// one 128B line), unroll-8 gathers in flight, masked tail.
// Phase 2: MFMA z @ W2 (cols zero-padded to 48) -> h2p (padded 128B rows).
#define ZSTR 72
#define H2STR 64
__global__ __launch_bounds__(256) void agg1mm_kernel(const f16* __restrict__ h1p,
                                                     const int* __restrict__ csr,
                                                     const int* __restrict__ row_start,
                                                     const int* __restrict__ cnt,
                                                     const float* __restrict__ dinv,
                                                     const float* __restrict__ b1,
                                                     const f16* __restrict__ w2f,
                                                     f16* __restrict__ h2p) {
    __shared__ f16 zT[64 * ZSTR];   // 9216 B
    int t = threadIdx.x;
    int nodeBase = blockIdx.x * 64;
    int wv = t >> 6;
    int L = t & 63;
    int g = L >> 3;       // node group 0..7 within wave
    int s = L & 7;        // sublane: f16x8 slot (dims 8s..8s+7)
    const f16x8* h8 = (const f16x8*)h1p;   // row stride 8 (f16x8 units)
    float bb[8];
#pragma unroll
    for (int j = 0; j < 8; ++j) bb[j] = b1[8 * s + j];

    for (int p = 0; p < 2; ++p) {
        int nodeLocal = 16 * wv + 8 * p + g;
        int node = nodeBase + nodeLocal;
        float acc[8];
#pragma unroll
        for (int j = 0; j < 8; ++j) acc[j] = 0.f;
        int lim = 0;
        const int* cp = csr;
        bool valid = (node < N_NODES);
        if (valid) {
            f16x8 sv = h8[(size_t)node * 8 + s];   // self loop
#pragma unroll
            for (int j = 0; j < 8; ++j) acc[j] = (float)sv[j];
            lim = cnt[node];
            cp = csr + row_start[node];
        }
        for (int k = 0; k < lim; k += 8) {
            int ii[8]; float mm[8];
#pragma unroll
            for (int u = 0; u < 8; ++u) {
                int kk = k + u;
                bool ok = (kk < lim);
                ii[u] = cp[ok ? kk : k];
                mm[u] = ok ? 1.f : 0.f;
            }
            f16x8 f[8];
#pragma unroll
            for (int u = 0; u < 8; ++u) f[u] = h8[(size_t)ii[u] * 8 + s];
#pragma unroll
            for (int j = 0; j < 8; ++j) {
                float t0 = 0.f;
#pragma unroll
                for (int u = 0; u < 8; ++u) t0 += mm[u] * (float)f[u][j];
                acc[j] += t0;
            }
        }
        f16x8 o;
        if (valid) {
            float di = dinv[node];
#pragma unroll
            for (int j = 0; j < 8; ++j) {
                float v = acc[j] * di + bb[j];
                o[j] = (f16)(v > 0.f ? v : 0.f);
            }
        } else {
#pragma unroll
            for (int j = 0; j < 8; ++j) o[j] = (f16)0.f;
        }
        *(f16x8*)&zT[nodeLocal * ZSTR + 8 * s] = o;
    }
    __syncthreads();

    // Phase 2: wave wv -> m-tile wv (nodes nodeBase+16*wv .. +15)
    int q = L >> 4, m = L & 15;
    const f16x8* w2f8 = (const f16x8*)w2f;
    f32x4 acc2[3] = {};
#pragma unroll
    for (int ks = 0; ks < 2; ++ks) {
        f16x8 afrag = *(const f16x8*)&zT[(16 * wv + m) * ZSTR + 32 * ks + 8 * q];
#pragma unroll
        for (int c = 0; c < 3; ++c)
            acc2[c] = __builtin_amdgcn_mfma_f32_16x16x32_f16(afrag, w2f8[(ks * 3 + c) * 64 + L], acc2[c], 0, 0, 0);
    }
#pragma unroll
    for (int r = 0; r < 4; ++r) {
        int node = nodeBase + 16 * wv + q * 4 + r;
        if (node < N_NODES) {
            float di = dinv[node];
            h2p[(size_t)node * H2STR + m]      = (f16)(acc2[0][r] * di);
            h2p[(size_t)node * H2STR + 16 + m] = (f16)(acc2[1][r] * di);
            if (m < 8)
                h2p[(size_t)node * H2STR + 32 + m] = (f16)(acc2[2][r] * di);
        }
    }
}

// agg2: 1 node per 5-lane group (each lane carries 16B of the 80B payload),
// h2p rows padded to 128B -> every gather is one aligned line.
// 12 nodes per wave, 48 nodes per block; unroll-8 with masked tail.
__global__ __launch_bounds__(256) void agg2_kernel(const f16* __restrict__ h2p,
                                                   const int* __restrict__ csr,
                                                   const int* __restrict__ row_start,
                                                   const int* __restrict__ cnt,
                                                   const float* __restrict__ dinv,
                                                   const float* __restrict__ b2,
                                                   float* __restrict__ out) {
    int t = threadIdx.x;
    int L = t & 63;
    int wv = t >> 6;
    int g = (L * 13) >> 6;            // == L/5 for L in [0,64)
    int s = L - 5 * g;                // == L%5 : f16x8 slot (dims 8s..8s+7)
    int node = blockIdx.x * 48 + wv * 12 + g;
    if (g >= 12 || node >= N_NODES) return;
    const f16x8* h8 = (const f16x8*)h2p;  // row stride 8 (f16x8 units, padded)
    float acc[8];
    {
        f16x8 sv = h8[(size_t)node * 8 + s];   // self loop
#pragma unroll
        for (int j = 0; j < 8; ++j) acc[j] = (float)sv[j];
    }
    int lim = cnt[node];
    const int* cp = csr + row_start[node];
    for (int k = 0; k < lim; k += 8) {
        int ii[8]; float mm[8];
#pragma unroll
        for (int u = 0; u < 8; ++u) {
            int kk = k + u;
            bool ok = (kk < lim);
            ii[u] = cp[ok ? kk : k];
            mm[u] = ok ? 1.f : 0.f;
        }
        f16x8 f[8];
#pragma unroll
        for (int u = 0; u < 8; ++u) f[u] = h8[(size_t)ii[u] * 8 + s];
#pragma unroll
        for (int j = 0; j < 8; ++j) {
            float t0 = 0.f;
#pragma unroll
            for (int u = 0; u < 8; ++u) t0 += mm[u] * (float)f[u][j];
            acc[j] += t0;
        }
    }
    float di = dinv[node];
    float4 o0, o1;
    o0.x = acc[0] * di + b2[8 * s + 0];
    o0.y = acc[1] * di + b2[8 * s + 1];
    o0.z = acc[2] * di + b2[8 * s + 2];
    o0.w = acc[3] * di + b2[8 * s + 3];
    o1.x = acc[4] * di + b2[8 * s + 4];
    o1.y = acc[5] * di + b2[8 * s + 5];
    o1.z = acc[6] * di + b2[8 * s + 6];
    o1.w = acc[7] * di + b2[8 * s + 7];
    *(float4*)&out[(size_t)node * OUT_DIM + 8 * s] = o0;
    *(float4*)&out[(size_t)node * OUT_DIM + 8 * s + 4] = o1;
}

extern "C" void kernel_launch(void* const* d_in, const int* in_sizes, int n_in,
                              void* d_out, int out_size, void* d_ws, size_t ws_size,
                              hipStream_t stream) {
    const float* x  = (const float*)d_in[0];
    const int*   ei = (const int*)d_in[1];      // [2, E] int32
    const float* W1 = (const float*)d_in[2];
    const float* b1 = (const float*)d_in[3];
    const float* W2 = (const float*)d_in[4];
    const float* b2 = (const float*)d_in[5];
    float* out = (float*)d_out;

    const int* src = ei;
    const int* dst = ei + N_EDGES;

    int* wsi        = (int*)d_ws;
    int* hist       = wsi;
    int* base       = hist + N_BUCKETS * N_CHUNKS;
    int* bucketTotal= base + N_BUCKETS * N_CHUNKS;
    int* bucketBase = bucketTotal + 1024;
    int* row_start  = bucketBase + 1024;
    int* cnt        = row_start + NPAD;
    int* csr        = cnt + NPAD;
    int* stage      = csr + N_EDGES;
    float* dinv     = (float*)(stage + N_EDGES);
    f16*   h1p      = (f16*)(dinv + NPAD);
    f16*   h2p      = h1p + (size_t)N_NODES * HID_DIM;
    f16*   w1f      = h2p + (size_t)N_NODES * H2STR;     // h2p padded: N*64 f16
    f16*   w2f      = w1f + 8192;                        // 3072 f16

    // D1: hist (transposed layout, int4 loads) + wfrag jobs
    hist_kernel<<<N_CHUNKS + 2, 1024, 0, stream>>>(dst, hist, W1, W2, w1f, w2f);
    // D2: per-bucket chunk scans (coalesced row reads)
    scan_chunks_kernel<<<N_BUCKETS, 256, 0, stream>>>(hist, base, bucketTotal);
    // D3: bucket-total scan
    scan_buckets_kernel<<<1, 256, 0, stream>>>(bucketTotal, bucketBase);
    // D4: scatter into bucket-grouped stage (int4 loads)
    scatter_kernel<<<N_CHUNKS, 1024, 0, stream>>>(src, dst, base, bucketBase, stage);
    // D5: place -> csr/row_start/cnt/dinv
    place_kernel<<<N_BUCKETS, 256, 0, stream>>>(stage, bucketBase, csr, row_start, cnt, dinv);
    // D6-D8: gemm1 -> fused agg1+gemm2 -> agg2
    gemm1_kernel<<<(N_NODES + 63) / 64, 256, 0, stream>>>(x, w1f, dinv, h1p);
    agg1mm_kernel<<<(N_NODES + 63) / 64, 256, 0, stream>>>(h1p, csr, row_start, cnt, dinv, b1, w2f, h2p);
    agg2_kernel<<<(N_NODES + 47) / 48, 256, 0, stream>>>(h2p, csr, row_start, cnt, dinv, b2, out);
}